// Round 2
// baseline (27694.891 us; speedup 1.0000x reference)
//
#include <hip/hip_runtime.h>
#include <hip/hip_bf16.h>

typedef __attribute__((ext_vector_type(4))) float f32x4;
typedef __attribute__((ext_vector_type(8))) __bf16 bf16x8;
typedef __attribute__((ext_vector_type(8))) unsigned short ushort8;

#define L_LAYERS 12
#define D_MODEL  1024
#define B_BATCH  16
#define T_TIME   2000
#define M_ROWS   (T_TIME * B_BATCH)   // 32000
#define H_HEADS  16
#define DH       64
#define SEGL     20
#define NSEG     (T_TIME / SEGL)      // 100

// ---------- helpers ----------
__device__ __forceinline__ void gload_lds16(const void* g, void* l) {
  __builtin_amdgcn_global_load_lds((const __attribute__((address_space(1))) void*)g,
                                   (__attribute__((address_space(3))) void*)l, 16, 0, 0);
}
__device__ __forceinline__ float bf2f(unsigned short u) {
  union { unsigned int i; float f; } x; x.i = ((unsigned)u) << 16; return x.f;
}
__device__ __forceinline__ unsigned short f2bf(float f) {
  union { __hip_bfloat16 h; unsigned short u; } x; x.h = __float2bfloat16(f); return x.u;
}

// ---------- x (B,T,D) -> h (T*B, D) fp32 ----------
__global__ __launch_bounds__(256)
void xpose(const float* __restrict__ x, float* __restrict__ h) {
  const int r = blockIdx.x;            // r = t*16 + b
  const int t = r >> 4, b = r & 15;
  reinterpret_cast<float4*>(h + (size_t)r * D_MODEL)[threadIdx.x] =
      reinterpret_cast<const float4*>(x + ((size_t)b * T_TIME + t) * D_MODEL)[threadIdx.x];
}

// ---------- weight transpose fp32 W[Kd][Nd] -> bf16 Wt[Nd][Kd], batched over z ----------
__global__ __launch_bounds__(256)
void trans_w(const float* __restrict__ W, __hip_bfloat16* __restrict__ Wt, int Kd, int Nd) {
  __shared__ float tbuf[32][33];
  const size_t base = (size_t)blockIdx.z * Kd * Nd;
  const int n0 = blockIdx.x * 32, k0 = blockIdx.y * 32;
  const int tx = threadIdx.x & 31, ty = threadIdx.x >> 5;
#pragma unroll
  for (int i = 0; i < 4; i++)
    tbuf[ty + i * 8][tx] = W[base + (size_t)(k0 + ty + i * 8) * Nd + n0 + tx];
  __syncthreads();
#pragma unroll
  for (int i = 0; i < 4; i++)
    Wt[base + (size_t)(n0 + ty + i * 8) * Kd + k0 + tx] = __float2bfloat16(tbuf[tx][ty + i * 8]);
}

// ---------- LayerNorm: fp32 in, bf16 or fp32 out (in-place safe: row read before write) ----------
template <int BF16OUT>
__global__ __launch_bounds__(256)
void ln_k(const float* __restrict__ in, void* __restrict__ out,
          const float* __restrict__ gamma, const float* __restrict__ beta) {
  const int r = blockIdx.x, t = threadIdx.x;
  const float4 v = reinterpret_cast<const float4*>(in + (size_t)r * D_MODEL)[t];
  float s  = v.x + v.y + v.z + v.w;
  float sq = v.x * v.x + v.y * v.y + v.z * v.z + v.w * v.w;
#pragma unroll
  for (int off = 32; off >= 1; off >>= 1) {
    s  += __shfl_xor(s, off);
    sq += __shfl_xor(sq, off);
  }
  __shared__ float ss[4], ssq[4];
  if ((t & 63) == 0) { ss[t >> 6] = s; ssq[t >> 6] = sq; }
  __syncthreads();
  s  = ss[0] + ss[1] + ss[2] + ss[3];
  sq = ssq[0] + ssq[1] + ssq[2] + ssq[3];
  const float mu   = s * (1.0f / D_MODEL);
  const float var  = sq * (1.0f / D_MODEL) - mu * mu;
  const float rstd = rsqrtf(var + 1e-5f);
  const float4 g = reinterpret_cast<const float4*>(gamma)[t];
  const float4 bb = reinterpret_cast<const float4*>(beta)[t];
  const float o0 = (v.x - mu) * rstd * g.x + bb.x;
  const float o1 = (v.y - mu) * rstd * g.y + bb.y;
  const float o2 = (v.z - mu) * rstd * g.z + bb.z;
  const float o3 = (v.w - mu) * rstd * g.w + bb.w;
  if constexpr (BF16OUT) {
    unsigned short pk[4] = {f2bf(o0), f2bf(o1), f2bf(o2), f2bf(o3)};
    *reinterpret_cast<uint2*>((__hip_bfloat16*)out + (size_t)r * D_MODEL + t * 4) =
        *reinterpret_cast<uint2*>(pk);
  } else {
    float4 o; o.x = o0; o.y = o1; o.z = o2; o.w = o3;
    reinterpret_cast<float4*>((float*)out)[(size_t)r * (D_MODEL / 4) + t] = o;
  }
}

// ---------- GEMM: C(MxN) = A(MxK bf16) * Bt(NxK bf16)^T, m97 structure ----------
// EPI_F32RES supports Cv == resid (each element read+written once by one thread).
enum { EPI_BF16 = 0, EPI_RELU = 1, EPI_F32RES = 2 };

template <int EPI>
__global__ __launch_bounds__(256)
void gemm_bt(const __hip_bfloat16* __restrict__ A, const __hip_bfloat16* __restrict__ Bt,
             const float* __restrict__ bias, const float* __restrict__ resid,
             void* __restrict__ Cv, int N, int K) {
  __shared__ __hip_bfloat16 As[128][32];
  __shared__ __hip_bfloat16 Bs[128][32];
  const int tid = threadIdx.x;
  const int wv = tid >> 6, ln = tid & 63;
  const int nt = blockIdx.x, mt = blockIdx.y;
  const __hip_bfloat16* ag = A  + ((size_t)mt * 128 + wv * 32 + (ln >> 2)) * K + (ln & 3) * 8;
  const __hip_bfloat16* bg = Bt + ((size_t)nt * 128 + wv * 32 + (ln >> 2)) * K + (ln & 3) * 8;
  __hip_bfloat16* asb0 = &As[wv * 32][0];
  __hip_bfloat16* asb1 = &As[wv * 32 + 16][0];
  __hip_bfloat16* bsb0 = &Bs[wv * 32][0];
  __hip_bfloat16* bsb1 = &Bs[wv * 32 + 16][0];
  const int wr = wv >> 1, wc = wv & 1;
  const int lr = ln & 15, lk = ln >> 4;
  f32x4 acc[4][4] = {};
  for (int k0 = 0; k0 < K; k0 += 32) {
    gload_lds16(ag + k0, asb0);
    gload_lds16(ag + (size_t)16 * K + k0, asb1);
    gload_lds16(bg + k0, bsb0);
    gload_lds16(bg + (size_t)16 * K + k0, bsb1);
    __syncthreads();
    bf16x8 af[4], bfr[4];
#pragma unroll
    for (int m = 0; m < 4; m++)
      af[m] = *reinterpret_cast<const bf16x8*>(&As[wr * 64 + m * 16 + lr][lk * 8]);
#pragma unroll
    for (int n = 0; n < 4; n++)
      bfr[n] = *reinterpret_cast<const bf16x8*>(&Bs[wc * 64 + n * 16 + lr][lk * 8]);
#pragma unroll
    for (int m = 0; m < 4; m++)
#pragma unroll
      for (int n = 0; n < 4; n++)
        acc[m][n] = __builtin_amdgcn_mfma_f32_16x16x32_bf16(af[m], bfr[n], acc[m][n], 0, 0, 0);
    __syncthreads();
  }
  // epilogue: C/D layout col=lane&15, row=(lane>>4)*4+j
#pragma unroll
  for (int n = 0; n < 4; n++) {
    const int col = nt * 128 + wc * 64 + n * 16 + lr;
    const float bv = bias[col];
#pragma unroll
    for (int m = 0; m < 4; m++) {
      const size_t rbase = (size_t)mt * 128 + wr * 64 + m * 16 + lk * 4;
#pragma unroll
      for (int j = 0; j < 4; j++) {
        const size_t idx = (rbase + j) * (size_t)N + col;
        float v = acc[m][n][j] + bv;
        if constexpr (EPI == EPI_RELU) v = fmaxf(v, 0.0f);
        if constexpr (EPI == EPI_F32RES) {
          ((float*)Cv)[idx] = v + resid[idx];
        } else {
          ((__hip_bfloat16*)Cv)[idx] = __float2bfloat16(v);
        }
      }
    }
  }
}

// ---------- block-diagonal attention (SEG=20, mask all-valid; ctx may alias q) ----------
__global__ __launch_bounds__(320)
void attn_k(const __hip_bfloat16* __restrict__ q, const __hip_bfloat16* __restrict__ kv,
            __hip_bfloat16* __restrict__ ctx) {
  __shared__ __hip_bfloat16 kls[SEGL][D_MODEL];
  __shared__ __hip_bfloat16 vls[SEGL][D_MODEL];
  const int sb = blockIdx.x;
  const int s = sb >> 4, b = sb & 15;
  const size_t row0 = (size_t)s * SEGL * B_BATCH + b;   // global row of (t=s*20, b)
  const int tid = threadIdx.x;
  // stage K,V: 20 rows x 1024 bf16 each (2560 16B chunks total)
  for (int c = tid; c < SEGL * 128; c += 320) {
    const int j = c >> 7;
    const int off = (c & 127) * 8;
    const size_t gr = (row0 + (size_t)j * B_BATCH) * (2 * D_MODEL);
    *reinterpret_cast<uint4*>(&kls[j][off]) = *reinterpret_cast<const uint4*>(kv + gr + off);
    *reinterpret_cast<uint4*>(&vls[j][off]) = *reinterpret_cast<const uint4*>(kv + gr + D_MODEL + off);
  }
  __syncthreads();
  const int hd = tid / SEGL, i = tid % SEGL;
  // q row -> regs (fp32). Loaded fully before ctx write -> ctx may alias q.
  float qr[64];
  const __hip_bfloat16* qp = q + (row0 + (size_t)i * B_BATCH) * D_MODEL + hd * DH;
#pragma unroll
  for (int d0 = 0; d0 < 64; d0 += 8) {
    ushort8 u = *reinterpret_cast<const ushort8*>(qp + d0);
#pragma unroll
    for (int e = 0; e < 8; e++) qr[d0 + e] = bf2f(u[e]);
  }
  // scores
  float sc[SEGL];
#pragma unroll
  for (int j = 0; j < SEGL; j++) {
    float a0 = 0, a1 = 0, a2 = 0, a3 = 0;
#pragma unroll
    for (int d0 = 0; d0 < 64; d0 += 8) {
      ushort8 u = *reinterpret_cast<const ushort8*>(&kls[j][hd * DH + d0]);
      a0 += qr[d0 + 0] * bf2f(u[0]); a1 += qr[d0 + 1] * bf2f(u[1]);
      a2 += qr[d0 + 2] * bf2f(u[2]); a3 += qr[d0 + 3] * bf2f(u[3]);
      a0 += qr[d0 + 4] * bf2f(u[4]); a1 += qr[d0 + 5] * bf2f(u[5]);
      a2 += qr[d0 + 6] * bf2f(u[6]); a3 += qr[d0 + 7] * bf2f(u[7]);
    }
    sc[j] = (a0 + a1 + a2 + a3) * 0.125f;   // 1/sqrt(64)
  }
  // softmax over 20
  float mx = sc[0];
#pragma unroll
  for (int j = 1; j < SEGL; j++) mx = fmaxf(mx, sc[j]);
  float sum = 0.0f;
#pragma unroll
  for (int j = 0; j < SEGL; j++) { sc[j] = __expf(sc[j] - mx); sum += sc[j]; }
  const float inv = 1.0f / sum;
  // ctx row (reuse qr as accumulator)
#pragma unroll
  for (int d = 0; d < 64; d++) qr[d] = 0.0f;
#pragma unroll
  for (int j = 0; j < SEGL; j++) {
    const float pj = sc[j] * inv;
#pragma unroll
    for (int d0 = 0; d0 < 64; d0 += 8) {
      ushort8 u = *reinterpret_cast<const ushort8*>(&vls[j][hd * DH + d0]);
      qr[d0 + 0] += pj * bf2f(u[0]); qr[d0 + 1] += pj * bf2f(u[1]);
      qr[d0 + 2] += pj * bf2f(u[2]); qr[d0 + 3] += pj * bf2f(u[3]);
      qr[d0 + 4] += pj * bf2f(u[4]); qr[d0 + 5] += pj * bf2f(u[5]);
      qr[d0 + 6] += pj * bf2f(u[6]); qr[d0 + 7] += pj * bf2f(u[7]);
    }
  }
  __hip_bfloat16* op = ctx + (row0 + (size_t)i * B_BATCH) * D_MODEL + hd * DH;
#pragma unroll
  for (int d0 = 0; d0 < 64; d0 += 8) {
    unsigned short pk[8];
#pragma unroll
    for (int e = 0; e < 8; e++) pk[e] = f2bf(qr[d0 + e]);
    *reinterpret_cast<uint4*>(op + d0) = *reinterpret_cast<uint4*>(pk);
  }
}

// ---------- final: pooled = mean_b h ; out = pooled @ fc_w + fc_b ----------
__global__ __launch_bounds__(256)
void pool_fc(const float* __restrict__ h, const float* __restrict__ fcw,
             const float* __restrict__ fcb, float* __restrict__ out) {
  const int t = blockIdx.x, tid = threadIdx.x;
  float ax = 0, ay = 0, az = 0, aw = 0;
#pragma unroll
  for (int b = 0; b < B_BATCH; b++) {
    float4 v = reinterpret_cast<const float4*>(h + ((size_t)t * B_BATCH + b) * D_MODEL)[tid];
    ax += v.x; ay += v.y; az += v.z; aw += v.w;
  }
  const int d0 = tid * 4;
  float pacc[5];
#pragma unroll
  for (int c = 0; c < 5; c++)
    pacc[c] = (ax * fcw[(d0 + 0) * 5 + c] + ay * fcw[(d0 + 1) * 5 + c] +
               az * fcw[(d0 + 2) * 5 + c] + aw * fcw[(d0 + 3) * 5 + c]) * (1.0f / B_BATCH);
#pragma unroll
  for (int off = 32; off >= 1; off >>= 1)
#pragma unroll
    for (int c = 0; c < 5; c++) pacc[c] += __shfl_xor(pacc[c], off);
  __shared__ float red[4][5];
  if ((tid & 63) == 0) {
#pragma unroll
    for (int c = 0; c < 5; c++) red[tid >> 6][c] = pacc[c];
  }
  __syncthreads();
  if (tid < 5)
    out[(size_t)t * 5 + tid] = red[0][tid] + red[1][tid] + red[2][tid] + red[3][tid] + fcb[tid];
}

// ---------- launch ----------
extern "C" void kernel_launch(void* const* d_in, const int* in_sizes, int n_in,
                              void* d_out, int out_size, void* d_ws, size_t ws_size,
                              hipStream_t stream) {
  const float* x    = (const float*)d_in[0];
  const float* lnp  = (const float*)d_in[2];
  const float* Wq   = (const float*)d_in[3];
  const float* bq   = (const float*)d_in[4];
  const float* Wkv  = (const float*)d_in[5];
  const float* bkv  = (const float*)d_in[6];
  const float* Wout = (const float*)d_in[7];
  const float* bout = (const float*)d_in[8];
  const float* W1   = (const float*)d_in[9];
  const float* b1   = (const float*)d_in[10];
  const float* W2   = (const float*)d_in[11];
  const float* b2   = (const float*)d_in[12];
  const float* fcw  = (const float*)d_in[13];
  const float* fcb  = (const float*)d_in[14];

  char* p = (char*)d_ws;
  size_t off = 0;
  auto take = [&](size_t bytes) -> char* { char* q = p + off; off += (bytes + 255) & ~(size_t)255; return q; };

  // Minimal-footprint activation set (~393 MB):
  //  h   : fp32 residual stream, updated in place
  //  hn  : bf16 LN output
  //  qb  : bf16 q; attention ctx written in place over qb
  //  kvb : bf16 [k|v]; FFN intermediate f1 reuses this buffer
  float* h            = (float*)take((size_t)M_ROWS * D_MODEL * 4);
  __hip_bfloat16* hn  = (__hip_bfloat16*)take((size_t)M_ROWS * D_MODEL * 2);
  __hip_bfloat16* qb  = (__hip_bfloat16*)take((size_t)M_ROWS * D_MODEL * 2);
  __hip_bfloat16* kvb = (__hip_bfloat16*)take((size_t)M_ROWS * 2 * D_MODEL * 2);
  __hip_bfloat16* f1  = kvb;   // alias: kv dead once ctx computed

  const size_t WU = (size_t)L_LAYERS * D_MODEL * D_MODEL * 2;  // one DxD bf16 tensor, all layers
  const bool full = ws_size >= off + 6 * WU + (size_t)(16 << 20);

  __hip_bfloat16 *WqT, *WkvT, *WoutT, *W1T, *W2T;
  if (full) {
    WqT   = (__hip_bfloat16*)take(WU);
    WkvT  = (__hip_bfloat16*)take(2 * WU);
    WoutT = (__hip_bfloat16*)take(WU);
    W1T   = (__hip_bfloat16*)take(WU);
    W2T   = (__hip_bfloat16*)take(WU);
    trans_w<<<dim3(32, 32, L_LAYERS), 256, 0, stream>>>(Wq,   WqT,   D_MODEL, D_MODEL);
    trans_w<<<dim3(64, 32, L_LAYERS), 256, 0, stream>>>(Wkv,  WkvT,  D_MODEL, 2 * D_MODEL);
    trans_w<<<dim3(32, 32, L_LAYERS), 256, 0, stream>>>(Wout, WoutT, D_MODEL, D_MODEL);
    trans_w<<<dim3(32, 32, L_LAYERS), 256, 0, stream>>>(W1,   W1T,   D_MODEL, D_MODEL);
    trans_w<<<dim3(32, 32, L_LAYERS), 256, 0, stream>>>(W2,   W2T,   D_MODEL, D_MODEL);
  } else {
    // per-layer staging (12 MB total)
    WqT   = (__hip_bfloat16*)take((size_t)D_MODEL * D_MODEL * 2);
    WkvT  = (__hip_bfloat16*)take((size_t)D_MODEL * 2 * D_MODEL * 2);
    WoutT = (__hip_bfloat16*)take((size_t)D_MODEL * D_MODEL * 2);
    W1T   = (__hip_bfloat16*)take((size_t)D_MODEL * D_MODEL * 2);
    W2T   = (__hip_bfloat16*)take((size_t)D_MODEL * D_MODEL * 2);
  }

  xpose<<<M_ROWS, 256, 0, stream>>>(x, h);

  for (int l = 0; l < L_LAYERS; l++) {
    const size_t lw = (size_t)l * D_MODEL * D_MODEL;
    const __hip_bfloat16* wq   = full ? WqT   + lw     : WqT;
    const __hip_bfloat16* wkv  = full ? WkvT  + 2 * lw : WkvT;
    const __hip_bfloat16* wout = full ? WoutT + lw     : WoutT;
    const __hip_bfloat16* w1   = full ? W1T   + lw     : W1T;
    const __hip_bfloat16* w2   = full ? W2T   + lw     : W2T;
    if (!full) {
      trans_w<<<dim3(32, 32, 1), 256, 0, stream>>>(Wq + lw,      WqT,   D_MODEL, D_MODEL);
      trans_w<<<dim3(64, 32, 1), 256, 0, stream>>>(Wkv + 2 * lw, WkvT,  D_MODEL, 2 * D_MODEL);
      trans_w<<<dim3(32, 32, 1), 256, 0, stream>>>(Wout + lw,    WoutT, D_MODEL, D_MODEL);
      trans_w<<<dim3(32, 32, 1), 256, 0, stream>>>(W1 + lw,      W1T,   D_MODEL, D_MODEL);
      trans_w<<<dim3(32, 32, 1), 256, 0, stream>>>(W2 + lw,      W2T,   D_MODEL, D_MODEL);
    }
    const float* g0 = lnp + ((size_t)l * 6 + 0) * D_MODEL;
    const float* g1 = lnp + ((size_t)l * 6 + 1) * D_MODEL;
    const float* g2 = lnp + ((size_t)l * 6 + 2) * D_MODEL;
    const float* g3 = lnp + ((size_t)l * 6 + 3) * D_MODEL;
    const float* g4 = lnp + ((size_t)l * 6 + 4) * D_MODEL;
    const float* g5 = lnp + ((size_t)l * 6 + 5) * D_MODEL;

    ln_k<1><<<M_ROWS, 256, 0, stream>>>(h, hn, g0, g1);
    gemm_bt<EPI_BF16>  <<<dim3(8, 250),  256, 0, stream>>>(hn, wq,  bq  + l * D_MODEL,     nullptr, qb,  D_MODEL,     D_MODEL);
    gemm_bt<EPI_BF16>  <<<dim3(16, 250), 256, 0, stream>>>(hn, wkv, bkv + l * 2 * D_MODEL, nullptr, kvb, 2 * D_MODEL, D_MODEL);
    attn_k<<<NSEG * B_BATCH, 320, 0, stream>>>(qb, kvb, qb);               // ctx in place over q
    gemm_bt<EPI_F32RES><<<dim3(8, 250),  256, 0, stream>>>(qb, wout, bout + l * D_MODEL, h, h, D_MODEL, D_MODEL);  // h += attn_out
    ln_k<1><<<M_ROWS, 256, 0, stream>>>(h, hn, g2, g3);
    gemm_bt<EPI_RELU>  <<<dim3(8, 250),  256, 0, stream>>>(hn, w1, b1 + l * D_MODEL, nullptr, f1, D_MODEL, D_MODEL);
    gemm_bt<EPI_F32RES><<<dim3(8, 250),  256, 0, stream>>>(f1, w2, b2 + l * D_MODEL, h, h, D_MODEL, D_MODEL);      // h += ffn
    ln_k<0><<<M_ROWS, 256, 0, stream>>>(h, h, g4, g5);                     // in-place post LN
  }

  pool_fc<<<T_TIME, 256, 0, stream>>>(h, fcw, fcb, (float*)d_out);
}

// Round 3
// 19203.835 us; speedup vs baseline: 1.4422x; 1.4422x over previous
//
#include <hip/hip_runtime.h>
#include <hip/hip_bf16.h>

typedef __attribute__((ext_vector_type(4))) float f32x4;
typedef __attribute__((ext_vector_type(8))) __bf16 bf16x8;
typedef __attribute__((ext_vector_type(8))) unsigned short ushort8;

#define L_LAYERS 12
#define D_MODEL  1024
#define B_BATCH  16
#define T_TIME   2000
#define M_ROWS   (T_TIME * B_BATCH)   // 32000
#define H_HEADS  16
#define DH       64
#define SEGL     20
#define NSEG     (T_TIME / SEGL)      // 100

// ---------- helpers ----------
__device__ __forceinline__ void gload_lds16(const void* g, void* l) {
  __builtin_amdgcn_global_load_lds((const __attribute__((address_space(1))) void*)g,
                                   (__attribute__((address_space(3))) void*)l, 16, 0, 0);
}
__device__ __forceinline__ float bf2f(unsigned short u) {
  union { unsigned int i; float f; } x; x.i = ((unsigned)u) << 16; return x.f;
}
__device__ __forceinline__ unsigned short f2bf(float f) {
  union { __hip_bfloat16 h; unsigned short u; } x; x.h = __float2bfloat16(f); return x.u;
}

// ---------- x (B,T,D) -> h (T*B, D) fp32 ----------
__global__ __launch_bounds__(256)
void xpose(const float* __restrict__ x, float* __restrict__ h) {
  const int r = blockIdx.x;            // r = t*16 + b
  const int t = r >> 4, b = r & 15;
  reinterpret_cast<float4*>(h + (size_t)r * D_MODEL)[threadIdx.x] =
      reinterpret_cast<const float4*>(x + ((size_t)b * T_TIME + t) * D_MODEL)[threadIdx.x];
}

// ---------- weight transpose fp32 W[Kd][Nd] -> bf16 Wt[Nd][Kd], batched over z ----------
__global__ __launch_bounds__(256)
void trans_w(const float* __restrict__ W, __hip_bfloat16* __restrict__ Wt, int Kd, int Nd) {
  __shared__ float tbuf[32][33];
  const size_t base = (size_t)blockIdx.z * Kd * Nd;
  const int n0 = blockIdx.x * 32, k0 = blockIdx.y * 32;
  const int tx = threadIdx.x & 31, ty = threadIdx.x >> 5;
#pragma unroll
  for (int i = 0; i < 4; i++)
    tbuf[ty + i * 8][tx] = W[base + (size_t)(k0 + ty + i * 8) * Nd + n0 + tx];
  __syncthreads();
#pragma unroll
  for (int i = 0; i < 4; i++)
    Wt[base + (size_t)(n0 + ty + i * 8) * Kd + k0 + tx] = __float2bfloat16(tbuf[tx][ty + i * 8]);
}

// ---------- LayerNorm: fp32 in, bf16 or fp32 out (in-place safe: row read before write) ----------
template <int BF16OUT>
__global__ __launch_bounds__(256)
void ln_k(const float* __restrict__ in, void* __restrict__ out,
          const float* __restrict__ gamma, const float* __restrict__ beta) {
  const int r = blockIdx.x, t = threadIdx.x;
  const float4 v = reinterpret_cast<const float4*>(in + (size_t)r * D_MODEL)[t];
  float s  = v.x + v.y + v.z + v.w;
  float sq = v.x * v.x + v.y * v.y + v.z * v.z + v.w * v.w;
#pragma unroll
  for (int off = 32; off >= 1; off >>= 1) {
    s  += __shfl_xor(s, off);
    sq += __shfl_xor(sq, off);
  }
  __shared__ float ss[4], ssq[4];
  if ((t & 63) == 0) { ss[t >> 6] = s; ssq[t >> 6] = sq; }
  __syncthreads();
  s  = ss[0] + ss[1] + ss[2] + ss[3];
  sq = ssq[0] + ssq[1] + ssq[2] + ssq[3];
  const float mu   = s * (1.0f / D_MODEL);
  const float var  = sq * (1.0f / D_MODEL) - mu * mu;
  const float rstd = rsqrtf(var + 1e-5f);
  const float4 g = reinterpret_cast<const float4*>(gamma)[t];
  const float4 bb = reinterpret_cast<const float4*>(beta)[t];
  const float o0 = (v.x - mu) * rstd * g.x + bb.x;
  const float o1 = (v.y - mu) * rstd * g.y + bb.y;
  const float o2 = (v.z - mu) * rstd * g.z + bb.z;
  const float o3 = (v.w - mu) * rstd * g.w + bb.w;
  if constexpr (BF16OUT) {
    unsigned short pk[4] = {f2bf(o0), f2bf(o1), f2bf(o2), f2bf(o3)};
    *reinterpret_cast<uint2*>((__hip_bfloat16*)out + (size_t)r * D_MODEL + t * 4) =
        *reinterpret_cast<uint2*>(pk);
  } else {
    float4 o; o.x = o0; o.y = o1; o.z = o2; o.w = o3;
    reinterpret_cast<float4*>((float*)out)[(size_t)r * (D_MODEL / 4) + t] = o;
  }
}

// ---------- GEMM: C(MxN) = A(MxK bf16) * Bt(NxK bf16)^T, m97 structure ----------
// EPI_F32RES supports Cv == resid (each element read+written once by one thread).
enum { EPI_BF16 = 0, EPI_RELU = 1, EPI_F32RES = 2 };

template <int EPI>
__global__ __launch_bounds__(256)
void gemm_bt(const __hip_bfloat16* __restrict__ A, const __hip_bfloat16* __restrict__ Bt,
             const float* __restrict__ bias, const float* __restrict__ resid,
             void* __restrict__ Cv, int N, int K) {
  __shared__ __hip_bfloat16 As[128][32];
  __shared__ __hip_bfloat16 Bs[128][32];
  const int tid = threadIdx.x;
  const int wv = tid >> 6, ln = tid & 63;
  const int nt = blockIdx.x, mt = blockIdx.y;
  const __hip_bfloat16* ag = A  + ((size_t)mt * 128 + wv * 32 + (ln >> 2)) * K + (ln & 3) * 8;
  const __hip_bfloat16* bg = Bt + ((size_t)nt * 128 + wv * 32 + (ln >> 2)) * K + (ln & 3) * 8;
  __hip_bfloat16* asb0 = &As[wv * 32][0];
  __hip_bfloat16* asb1 = &As[wv * 32 + 16][0];
  __hip_bfloat16* bsb0 = &Bs[wv * 32][0];
  __hip_bfloat16* bsb1 = &Bs[wv * 32 + 16][0];
  const int wr = wv >> 1, wc = wv & 1;
  const int lr = ln & 15, lk = ln >> 4;
  f32x4 acc[4][4] = {};
  for (int k0 = 0; k0 < K; k0 += 32) {
    gload_lds16(ag + k0, asb0);
    gload_lds16(ag + (size_t)16 * K + k0, asb1);
    gload_lds16(bg + k0, bsb0);
    gload_lds16(bg + (size_t)16 * K + k0, bsb1);
    __syncthreads();
    bf16x8 af[4], bfr[4];
#pragma unroll
    for (int m = 0; m < 4; m++)
      af[m] = *reinterpret_cast<const bf16x8*>(&As[wr * 64 + m * 16 + lr][lk * 8]);
#pragma unroll
    for (int n = 0; n < 4; n++)
      bfr[n] = *reinterpret_cast<const bf16x8*>(&Bs[wc * 64 + n * 16 + lr][lk * 8]);
#pragma unroll
    for (int m = 0; m < 4; m++)
#pragma unroll
      for (int n = 0; n < 4; n++)
        acc[m][n] = __builtin_amdgcn_mfma_f32_16x16x32_bf16(af[m], bfr[n], acc[m][n], 0, 0, 0);
    __syncthreads();
  }
  // epilogue: C/D layout col=lane&15, row=(lane>>4)*4+j
#pragma unroll
  for (int n = 0; n < 4; n++) {
    const int col = nt * 128 + wc * 64 + n * 16 + lr;
    const float bv = bias[col];
#pragma unroll
    for (int m = 0; m < 4; m++) {
      const size_t rbase = (size_t)mt * 128 + wr * 64 + m * 16 + lk * 4;
#pragma unroll
      for (int j = 0; j < 4; j++) {
        const size_t idx = (rbase + j) * (size_t)N + col;
        float v = acc[m][n][j] + bv;
        if constexpr (EPI == EPI_RELU) v = fmaxf(v, 0.0f);
        if constexpr (EPI == EPI_F32RES) {
          ((float*)Cv)[idx] = v + resid[idx];
        } else {
          ((__hip_bfloat16*)Cv)[idx] = __float2bfloat16(v);
        }
      }
    }
  }
}

// ---------- block-diagonal attention (SEG=20, mask all-valid; ctx may alias q) ----------
// Spill-free restructure: q kept as PACKED bf16 (8x ushort8 = 32 VGPRs), PV accumulation
// is d-chunk-outer / j-inner so only 8 fp32 accumulators are live at a time.
__global__ __launch_bounds__(320)
void attn_k(const __hip_bfloat16* __restrict__ q, const __hip_bfloat16* __restrict__ kv,
            __hip_bfloat16* __restrict__ ctx) {
  __shared__ __hip_bfloat16 kls[SEGL][D_MODEL];
  __shared__ __hip_bfloat16 vls[SEGL][D_MODEL];
  const int sb = blockIdx.x;
  const int s = sb >> 4, b = sb & 15;
  const size_t row0 = (size_t)s * SEGL * B_BATCH + b;   // global row of (t=s*20, b)
  const int tid = threadIdx.x;
  // stage K,V: 20 rows x 1024 bf16 each
  for (int c = tid; c < SEGL * 128; c += 320) {
    const int j = c >> 7;
    const int off = (c & 127) * 8;
    const size_t gr = (row0 + (size_t)j * B_BATCH) * (2 * D_MODEL);
    *reinterpret_cast<uint4*>(&kls[j][off]) = *reinterpret_cast<const uint4*>(kv + gr + off);
    *reinterpret_cast<uint4*>(&vls[j][off]) = *reinterpret_cast<const uint4*>(kv + gr + D_MODEL + off);
  }
  __syncthreads();
  const int hd = tid / SEGL, i = tid % SEGL;
  // q row, packed bf16: 8 x ushort8 = 32 VGPRs
  ushort8 qv[8];
  const __hip_bfloat16* qp = q + (row0 + (size_t)i * B_BATCH) * D_MODEL + hd * DH;
#pragma unroll
  for (int c = 0; c < 8; c++) qv[c] = reinterpret_cast<const ushort8*>(qp)[c];
  // scores (unpack q on the fly; VALU is nearly idle here)
  float sc[SEGL];
#pragma unroll
  for (int j = 0; j < SEGL; j++) {
    float a0 = 0, a1 = 0;
#pragma unroll
    for (int c = 0; c < 8; c++) {
      ushort8 u = *reinterpret_cast<const ushort8*>(&kls[j][hd * DH + c * 8]);
#pragma unroll
      for (int e = 0; e < 8; e += 2) {
        a0 += bf2f(qv[c][e]) * bf2f(u[e]);
        a1 += bf2f(qv[c][e + 1]) * bf2f(u[e + 1]);
      }
    }
    sc[j] = (a0 + a1) * 0.125f;   // 1/sqrt(64)
  }
  // softmax over 20, fold 1/sum into sc
  float mx = sc[0];
#pragma unroll
  for (int j = 1; j < SEGL; j++) mx = fmaxf(mx, sc[j]);
  float sum = 0.0f;
#pragma unroll
  for (int j = 0; j < SEGL; j++) { sc[j] = __expf(sc[j] - mx); sum += sc[j]; }
  const float inv = 1.0f / sum;
#pragma unroll
  for (int j = 0; j < SEGL; j++) sc[j] *= inv;
  // PV: d-chunk-outer (8 accumulators live), immediate 16B store per chunk.
  // q fully consumed above -> ctx may alias q (same thread's own region).
  __hip_bfloat16* op = ctx + (row0 + (size_t)i * B_BATCH) * D_MODEL + hd * DH;
#pragma unroll
  for (int d0 = 0; d0 < 64; d0 += 8) {
    float acc[8] = {};
#pragma unroll
    for (int j = 0; j < SEGL; j++) {
      ushort8 u = *reinterpret_cast<const ushort8*>(&vls[j][hd * DH + d0]);
#pragma unroll
      for (int e = 0; e < 8; e++) acc[e] += sc[j] * bf2f(u[e]);
    }
    unsigned short pk[8];
#pragma unroll
    for (int e = 0; e < 8; e++) pk[e] = f2bf(acc[e]);
    *reinterpret_cast<uint4*>(op + d0) = *reinterpret_cast<uint4*>(pk);
  }
}

// ---------- final: pooled = mean_b h ; out = pooled @ fc_w + fc_b ----------
__global__ __launch_bounds__(256)
void pool_fc(const float* __restrict__ h, const float* __restrict__ fcw,
             const float* __restrict__ fcb, float* __restrict__ out) {
  const int t = blockIdx.x, tid = threadIdx.x;
  float ax = 0, ay = 0, az = 0, aw = 0;
#pragma unroll
  for (int b = 0; b < B_BATCH; b++) {
    float4 v = reinterpret_cast<const float4*>(h + ((size_t)t * B_BATCH + b) * D_MODEL)[tid];
    ax += v.x; ay += v.y; az += v.z; aw += v.w;
  }
  const int d0 = tid * 4;
  float pacc[5];
#pragma unroll
  for (int c = 0; c < 5; c++)
    pacc[c] = (ax * fcw[(d0 + 0) * 5 + c] + ay * fcw[(d0 + 1) * 5 + c] +
               az * fcw[(d0 + 2) * 5 + c] + aw * fcw[(d0 + 3) * 5 + c]) * (1.0f / B_BATCH);
#pragma unroll
  for (int off = 32; off >= 1; off >>= 1)
#pragma unroll
    for (int c = 0; c < 5; c++) pacc[c] += __shfl_xor(pacc[c], off);
  __shared__ float red[4][5];
  if ((tid & 63) == 0) {
#pragma unroll
    for (int c = 0; c < 5; c++) red[tid >> 6][c] = pacc[c];
  }
  __syncthreads();
  if (tid < 5)
    out[(size_t)t * 5 + tid] = red[0][tid] + red[1][tid] + red[2][tid] + red[3][tid] + fcb[tid];
}

// ---------- launch ----------
extern "C" void kernel_launch(void* const* d_in, const int* in_sizes, int n_in,
                              void* d_out, int out_size, void* d_ws, size_t ws_size,
                              hipStream_t stream) {
  const float* x    = (const float*)d_in[0];
  const float* lnp  = (const float*)d_in[2];
  const float* Wq   = (const float*)d_in[3];
  const float* bq   = (const float*)d_in[4];
  const float* Wkv  = (const float*)d_in[5];
  const float* bkv  = (const float*)d_in[6];
  const float* Wout = (const float*)d_in[7];
  const float* bout = (const float*)d_in[8];
  const float* W1   = (const float*)d_in[9];
  const float* b1   = (const float*)d_in[10];
  const float* W2   = (const float*)d_in[11];
  const float* b2   = (const float*)d_in[12];
  const float* fcw  = (const float*)d_in[13];
  const float* fcb  = (const float*)d_in[14];

  char* p = (char*)d_ws;
  size_t off = 0;
  auto take = [&](size_t bytes) -> char* { char* q = p + off; off += (bytes + 255) & ~(size_t)255; return q; };

  // Minimal-footprint activation set (~393 MB):
  //  h   : fp32 residual stream, updated in place
  //  hn  : bf16 LN output
  //  qb  : bf16 q; attention ctx written in place over qb
  //  kvb : bf16 [k|v]; FFN intermediate f1 reuses this buffer
  float* h            = (float*)take((size_t)M_ROWS * D_MODEL * 4);
  __hip_bfloat16* hn  = (__hip_bfloat16*)take((size_t)M_ROWS * D_MODEL * 2);
  __hip_bfloat16* qb  = (__hip_bfloat16*)take((size_t)M_ROWS * D_MODEL * 2);
  __hip_bfloat16* kvb = (__hip_bfloat16*)take((size_t)M_ROWS * 2 * D_MODEL * 2);
  __hip_bfloat16* f1  = kvb;   // alias: kv dead once ctx computed

  const size_t WU = (size_t)L_LAYERS * D_MODEL * D_MODEL * 2;  // one DxD bf16 tensor, all layers
  const bool full = ws_size >= off + 6 * WU + (size_t)(16 << 20);

  __hip_bfloat16 *WqT, *WkvT, *WoutT, *W1T, *W2T;
  if (full) {
    WqT   = (__hip_bfloat16*)take(WU);
    WkvT  = (__hip_bfloat16*)take(2 * WU);
    WoutT = (__hip_bfloat16*)take(WU);
    W1T   = (__hip_bfloat16*)take(WU);
    W2T   = (__hip_bfloat16*)take(WU);
    trans_w<<<dim3(32, 32, L_LAYERS), 256, 0, stream>>>(Wq,   WqT,   D_MODEL, D_MODEL);
    trans_w<<<dim3(64, 32, L_LAYERS), 256, 0, stream>>>(Wkv,  WkvT,  D_MODEL, 2 * D_MODEL);
    trans_w<<<dim3(32, 32, L_LAYERS), 256, 0, stream>>>(Wout, WoutT, D_MODEL, D_MODEL);
    trans_w<<<dim3(32, 32, L_LAYERS), 256, 0, stream>>>(W1,   W1T,   D_MODEL, D_MODEL);
    trans_w<<<dim3(32, 32, L_LAYERS), 256, 0, stream>>>(W2,   W2T,   D_MODEL, D_MODEL);
  } else {
    // per-layer staging (12 MB total)
    WqT   = (__hip_bfloat16*)take((size_t)D_MODEL * D_MODEL * 2);
    WkvT  = (__hip_bfloat16*)take((size_t)D_MODEL * 2 * D_MODEL * 2);
    WoutT = (__hip_bfloat16*)take((size_t)D_MODEL * D_MODEL * 2);
    W1T   = (__hip_bfloat16*)take((size_t)D_MODEL * D_MODEL * 2);
    W2T   = (__hip_bfloat16*)take((size_t)D_MODEL * D_MODEL * 2);
  }

  xpose<<<M_ROWS, 256, 0, stream>>>(x, h);

  for (int l = 0; l < L_LAYERS; l++) {
    const size_t lw = (size_t)l * D_MODEL * D_MODEL;
    const __hip_bfloat16* wq   = full ? WqT   + lw     : WqT;
    const __hip_bfloat16* wkv  = full ? WkvT  + 2 * lw : WkvT;
    const __hip_bfloat16* wout = full ? WoutT + lw     : WoutT;
    const __hip_bfloat16* w1   = full ? W1T   + lw     : W1T;
    const __hip_bfloat16* w2   = full ? W2T   + lw     : W2T;
    if (!full) {
      trans_w<<<dim3(32, 32, 1), 256, 0, stream>>>(Wq + lw,      WqT,   D_MODEL, D_MODEL);
      trans_w<<<dim3(64, 32, 1), 256, 0, stream>>>(Wkv + 2 * lw, WkvT,  D_MODEL, 2 * D_MODEL);
      trans_w<<<dim3(32, 32, 1), 256, 0, stream>>>(Wout + lw,    WoutT, D_MODEL, D_MODEL);
      trans_w<<<dim3(32, 32, 1), 256, 0, stream>>>(W1 + lw,      W1T,   D_MODEL, D_MODEL);
      trans_w<<<dim3(32, 32, 1), 256, 0, stream>>>(W2 + lw,      W2T,   D_MODEL, D_MODEL);
    }
    const float* g0 = lnp + ((size_t)l * 6 + 0) * D_MODEL;
    const float* g1 = lnp + ((size_t)l * 6 + 1) * D_MODEL;
    const float* g2 = lnp + ((size_t)l * 6 + 2) * D_MODEL;
    const float* g3 = lnp + ((size_t)l * 6 + 3) * D_MODEL;
    const float* g4 = lnp + ((size_t)l * 6 + 4) * D_MODEL;
    const float* g5 = lnp + ((size_t)l * 6 + 5) * D_MODEL;

    ln_k<1><<<M_ROWS, 256, 0, stream>>>(h, hn, g0, g1);
    gemm_bt<EPI_BF16>  <<<dim3(8, 250),  256, 0, stream>>>(hn, wq,  bq  + l * D_MODEL,     nullptr, qb,  D_MODEL,     D_MODEL);
    gemm_bt<EPI_BF16>  <<<dim3(16, 250), 256, 0, stream>>>(hn, wkv, bkv + l * 2 * D_MODEL, nullptr, kvb, 2 * D_MODEL, D_MODEL);
    attn_k<<<NSEG * B_BATCH, 320, 0, stream>>>(qb, kvb, qb);               // ctx in place over q
    gemm_bt<EPI_F32RES><<<dim3(8, 250),  256, 0, stream>>>(qb, wout, bout + l * D_MODEL, h, h, D_MODEL, D_MODEL);  // h += attn_out
    ln_k<1><<<M_ROWS, 256, 0, stream>>>(h, hn, g2, g3);
    gemm_bt<EPI_RELU>  <<<dim3(8, 250),  256, 0, stream>>>(hn, w1, b1 + l * D_MODEL, nullptr, f1, D_MODEL, D_MODEL);
    gemm_bt<EPI_F32RES><<<dim3(8, 250),  256, 0, stream>>>(f1, w2, b2 + l * D_MODEL, h, h, D_MODEL, D_MODEL);      // h += ffn
    ln_k<0><<<M_ROWS, 256, 0, stream>>>(h, h, g4, g5);                     // in-place post LN
  }

  pool_fc<<<T_TIME, 256, 0, stream>>>(h, fcw, fcb, (float*)d_out);
}